// Round 2
// baseline (3295.692 us; speedup 1.0000x reference)
//
#include <hip/hip_runtime.h>
#include <math.h>

#define VOCAB 1000
#define EMB   128
#define HID   256
#define G4    1024   // 4*HID
#define BATCH 64
#define SEQT  1024
#define KV    128    // ALL half2 cols in the unified VGPR/AGPR file

typedef unsigned int u32;
typedef _Float16 f16;
typedef __attribute__((ext_vector_type(2))) _Float16 h2v;
union H2U { u32 u; h2v h; unsigned short s[2]; };

#if defined(__has_builtin)
# if __has_builtin(__builtin_amdgcn_fdot2)
#  define HAVE_FDOT2 1
# endif
#endif
__device__ __forceinline__ float fdot2_(u32 a, u32 b, float c) {
    H2U ua, ub; ua.u = a; ub.u = b;
#ifdef HAVE_FDOT2
    return __builtin_amdgcn_fdot2(ua.h, ub.h, c, false);   // v_dot2_f32_f16
#else
    return c + (float)ua.h.x * (float)ub.h.x + (float)ua.h.y * (float)ub.h.y;
#endif
}

__device__ __forceinline__ float sigmoidf_(float x) {
    return 1.f / (1.f + __expf(-x));
}
__device__ __forceinline__ float tanhf_(float x) {
    return 1.f - 2.f / (__expf(2.f * x) + 1.f);
}

// ---------------------------------------------------------------------------
// Kernel 1: eproj[v][g] = emb[v] . W_ih[g] + b_ih[g] + b_hh[g]   (fp32, exact)
// ---------------------------------------------------------------------------
__global__ __launch_bounds__(1024) void eproj_kernel(
    const float* __restrict__ emb, const float* __restrict__ W_ih,
    const float* __restrict__ b_ih, const float* __restrict__ b_hh,
    float* __restrict__ eproj)
{
    const int v = blockIdx.x;
    const int g = threadIdx.x;
    __shared__ __align__(16) float x_sh[EMB];
    if (g < EMB / 4) {
        ((float4*)x_sh)[g] = ((const float4*)(emb + (size_t)v * EMB))[g];
    }
    __syncthreads();
    const float4* wrow = (const float4*)(W_ih + (size_t)g * EMB);
    float a0 = 0.f, a1 = 0.f, a2 = 0.f, a3 = 0.f;
#pragma unroll
    for (int e4 = 0; e4 < EMB / 4; e4++) {
        float4 wv = wrow[e4];
        float4 xv = ((const float4*)x_sh)[e4];
        a0 += wv.x * xv.x;
        a1 += wv.y * xv.y;
        a2 += wv.z * xv.z;
        a3 += wv.w * xv.w;
    }
    eproj[(size_t)v * G4 + g] = (a0 + a1) + (a2 + a3) + b_ih[g] + b_hh[g];
}

// ---------------------------------------------------------------------------
// Kernel 2: pack W_hh fp32 -> fp16 half2 into one [chunk][row][4] u32 array
// (32 chunks of 4 half2-cols x 1024 rows). [chunk][row][4] makes the
// prologue global dwordx4 loads lane-consecutive (coalesced).
// ---------------------------------------------------------------------------
__global__ __launch_bounds__(128) void pack_whh(
    const float* __restrict__ Whh, u32* __restrict__ wvq)
{
    const int r = blockIdx.x;        // row 0..1023
    const int m = threadIdx.x;       // half2 col 0..127
    H2U u;
    u.h.x = (f16)Whh[(size_t)r * HID + 2 * m];
    u.h.y = (f16)Whh[(size_t)r * HID + 2 * m + 1];
    wvq[(size_t)(m >> 2) * (G4 * 4) + r * 4 + (m & 3)] = u.u;
}

// ---------------------------------------------------------------------------
// Kernel 3: single-CU LSTM, fully register-resident weights. One block
// (512 thr, 8 waves, 2 waves/SIMD) per batch element. At 2 waves/SIMD each
// wave may allocate up to 512 unified regs (2x512 <= 2048 pool), so thread
// tau holds BOTH its gate rows (tau: i/f, 512+tau: g/o) entirely in the
// unified VGPR+AGPR file: 2 x 128 half2 = 256 persistent u32. The compiler
// places the overflow past ~220 arch VGPRs into AGPRs (gfx950 unified file,
// as observed in the 120-VGPR/184-reg variant). Per-step LDS traffic is now
// ONLY the 32 uniform-address h-broadcast b128 reads + the 2 KB gate bounce
// -- the 144 KB/step lane-spread weight-tail reads (~1700 cy/step on the
// LDS pipe, ~45% of step time) are gone. Zero cross-CU traffic.
// ---------------------------------------------------------------------------
__global__ __launch_bounds__(512, 2) void lstm_single_cu(
    const int* __restrict__ ids, const int* __restrict__ lens,
    const float* __restrict__ eproj,
    const u32* __restrict__ wvq,
    float* __restrict__ out)
{
    const int b   = blockIdx.x;
    const int tau = threadIdx.x;                 // 0..511
    const int rA  = tau;                         // gate i (tau<256) / f
    const int rB  = 512 + tau;                   // gate g (tau<256) / o

    __shared__ u32   h2_sh[2][HID / 2];          // h as half2, parity x2
    __shared__ float gs_f[HID], gs_o[HID];       // f,o gate-sum bounce
    __shared__ int   id_sh[SEQT];                // this block's id row (4 KB)

    const int* idr = ids + (size_t)b * SEQT;
    ((int2*)id_sh)[tau] = ((const int2*)idr)[tau];   // 512 x 8B = 4 KB
    if (tau < HID / 2) h2_sh[0][tau] = 0u;           // h(0) = 0

    // persistent weights: 2 rows x 128 half2 = 256 u32 in VGPR+AGPR
    u32 wA[KV], wB[KV];
#pragma unroll
    for (int q = 0; q < KV / 4; q++) {
        uint4 ta = ((const uint4*)wvq)[q * G4 + rA];
        uint4 tb = ((const uint4*)wvq)[q * G4 + rB];
        wA[4 * q + 0] = ta.x; wA[4 * q + 1] = ta.y;
        wA[4 * q + 2] = ta.z; wA[4 * q + 3] = ta.w;
        wB[4 * q + 0] = tb.x; wB[4 * q + 1] = tb.y;
        wB[4 * q + 2] = tb.z; wB[4 * q + 3] = tb.w;
    }

    const int len = lens[b];                     // >= 1
    float c = 0.f, hf = 0.f;

    const float* e0 = eproj + (size_t)idr[0] * G4;
    float xA = e0[rA], xB = e0[rB];

    __syncthreads();

    for (int t = 0; t < len; t++) {
        // prefetch next step's input projections (hidden under dot loops)
        const int nt = (t + 1 < len) ? t + 1 : len - 1;
        const int nid = id_sh[nt];
        const float* en = eproj + (size_t)nid * G4;
        const float nA = en[rA], nB = en[rB];

        const int p = t & 1;
        const uint4* hb4 = (const uint4*)h2_sh[p];   // 32 b128 broadcasts
        float aA = xA, aB = xB;

#pragma unroll
        for (int q = 0; q < KV / 4; q++) {
            uint4 h4 = hb4[q];
            aA = fdot2_(wA[4 * q + 0], h4.x, aA);
            aB = fdot2_(wB[4 * q + 0], h4.x, aB);
            aA = fdot2_(wA[4 * q + 1], h4.y, aA);
            aB = fdot2_(wB[4 * q + 1], h4.y, aB);
            aA = fdot2_(wA[4 * q + 2], h4.z, aA);
            aB = fdot2_(wB[4 * q + 2], h4.z, aB);
            aA = fdot2_(wA[4 * q + 3], h4.w, aA);
            aB = fdot2_(wB[4 * q + 3], h4.w, aB);
        }

        if (tau >= HID) {            // rows f,o: pass sums to unit owner
            gs_f[tau - HID] = aA;
            gs_o[tau - HID] = aB;
        }
        __syncthreads();             // barrier A: sums visible

        if (tau < HID) {             // unit owner: i,g local + f,o from LDS
            float ig = sigmoidf_(aA);
            float gg = tanhf_(aB);
            float fg = sigmoidf_(gs_f[tau]);
            float og = sigmoidf_(gs_o[tau]);
            c = fg * c + ig * gg;
            hf = og * tanhf_(c);
            H2U hv; hv.h.x = (f16)hf; hv.h.y = (f16)0.f;
            ((unsigned short*)h2_sh[p ^ 1])[tau] = hv.s[0];
        }
        xA = nA; xB = nB;
        __syncthreads();             // barrier B: h(t+1) published
    }

    if (tau < HID) out[(size_t)b * HID + tau] = hf;
}

// ---------------------------------------------------------------------------
// Fallback (ws too small): correct-but-slow single-block fp32 version.
// ---------------------------------------------------------------------------
__global__ __launch_bounds__(1024, 1) void lstm_fallback(
    const int* __restrict__ ids, const int* __restrict__ lens,
    const float* __restrict__ emb, const float* __restrict__ W_ih,
    const float* __restrict__ b_ih, const float* __restrict__ b_hh,
    const float* __restrict__ W_hh, float* __restrict__ out)
{
    const int b = blockIdx.x;
    const int t = threadIdx.x;

    __shared__ __align__(16) float h_sh[HID];
    __shared__ __align__(16) float c_sh[HID];
    __shared__ __align__(16) float gates[G4];
    __shared__ __align__(16) float x_sh[EMB];

    float wih[EMB];
    {
        const float4* wr = (const float4*)(W_ih + (size_t)t * EMB);
#pragma unroll
        for (int e4 = 0; e4 < EMB / 4; e4++) {
            float4 wv = wr[e4];
            wih[4 * e4 + 0] = wv.x;
            wih[4 * e4 + 1] = wv.y;
            wih[4 * e4 + 2] = wv.z;
            wih[4 * e4 + 3] = wv.w;
        }
    }
    float bias = b_ih[t] + b_hh[t];

    const int len = lens[b];
    const int* ids_row = ids + (size_t)b * SEQT;
    if (t < HID) { h_sh[t] = 0.f; c_sh[t] = 0.f; }
    __syncthreads();

    for (int step = 0; step < len; step++) {
        int id = ids_row[step];
        if (t < EMB / 4) {
            ((float4*)x_sh)[t] = ((const float4*)(emb + (size_t)id * EMB))[t];
        }
        __syncthreads();
        float a0 = bias, a1 = 0.f, a2 = 0.f, a3 = 0.f;
#pragma unroll
        for (int e4 = 0; e4 < EMB / 4; e4++) {
            float4 xv = ((const float4*)x_sh)[e4];
            a0 += wih[4 * e4 + 0] * xv.x;
            a1 += wih[4 * e4 + 1] * xv.y;
            a2 += wih[4 * e4 + 2] * xv.z;
            a3 += wih[4 * e4 + 3] * xv.w;
        }
        float acc = (a0 + a1) + (a2 + a3);

        const float* wrow = W_hh + (size_t)t * HID;
        a0 = acc; a1 = 0.f; a2 = 0.f; a3 = 0.f;
        for (int k4 = 0; k4 < HID / 4; k4++) {
            float4 hv = ((const float4*)h_sh)[k4];
            float4 wv = ((const float4*)wrow)[k4];
            a0 += wv.x * hv.x;
            a1 += wv.y * hv.y;
            a2 += wv.z * hv.z;
            a3 += wv.w * hv.w;
        }
        gates[t] = (a0 + a1) + (a2 + a3);
        __syncthreads();

        if (t < HID) {
            float ig = sigmoidf_(gates[t]);
            float fg = sigmoidf_(gates[HID + t]);
            float gg = tanhf_(gates[2 * HID + t]);
            float og = sigmoidf_(gates[3 * HID + t]);
            float cc = fg * c_sh[t] + ig * gg;
            c_sh[t] = cc;
            h_sh[t] = og * tanhf_(cc);
        }
        __syncthreads();
    }
    if (t < HID) out[(size_t)b * HID + t] = h_sh[t];
}

extern "C" void kernel_launch(void* const* d_in, const int* in_sizes, int n_in,
                              void* d_out, int out_size, void* d_ws, size_t ws_size,
                              hipStream_t stream) {
    const int*   ids  = (const int*)d_in[0];
    const int*   lens = (const int*)d_in[1];
    const float* emb  = (const float*)d_in[2];
    const float* Wih  = (const float*)d_in[3];
    const float* Whh  = (const float*)d_in[4];
    const float* bih  = (const float*)d_in[5];
    const float* bhh  = (const float*)d_in[6];
    float* out = (float*)d_out;

    // ws layout: eproj 4 MB | wvq 512 KB
    const size_t ep_bytes = (size_t)VOCAB * G4 * sizeof(float);
    const size_t wv_off   = ep_bytes;
    const size_t wv_bytes = (size_t)(KV / 4) * G4 * 4 * sizeof(u32);

    if (ws_size >= wv_off + wv_bytes) {
        float* eproj = (float*)d_ws;
        u32*   wvp   = (u32*)((char*)d_ws + wv_off);
        eproj_kernel<<<VOCAB, 1024, 0, stream>>>(emb, Wih, bih, bhh, eproj);
        pack_whh<<<G4, 128, 0, stream>>>(Whh, wvp);
        lstm_single_cu<<<BATCH, 512, 0, stream>>>(ids, lens, eproj, wvp, out);
    } else {
        lstm_fallback<<<BATCH, 1024, 0, stream>>>(
            ids, lens, emb, Wih, bih, bhh, Whh, out);
    }
}

// Round 3
// 2121.293 us; speedup vs baseline: 1.5536x; 1.5536x over previous
//
#include <hip/hip_runtime.h>
#include <math.h>

#define VOCAB 1000
#define EMB   128
#define HID   256
#define G4    1024   // 4*HID
#define BATCH 64
#define SEQT  1024
#define KV    92     // half2 cols in VGPRs  (k in [0,184))
#define KL    36     // half2 cols in LDS    (k in [184,256)), 9 b128 chunks

typedef unsigned int u32;
typedef _Float16 f16;
typedef __attribute__((ext_vector_type(2))) _Float16 h2v;
union H2U { u32 u; h2v h; unsigned short s[2]; };

#if defined(__has_builtin)
# if __has_builtin(__builtin_amdgcn_fdot2)
#  define HAVE_FDOT2 1
# endif
#endif
__device__ __forceinline__ float fdot2_(u32 a, u32 b, float c) {
    H2U ua, ub; ua.u = a; ub.u = b;
#ifdef HAVE_FDOT2
    return __builtin_amdgcn_fdot2(ua.h, ub.h, c, false);   // v_dot2_f32_f16
#else
    return c + (float)ua.h.x * (float)ub.h.x + (float)ua.h.y * (float)ub.h.y;
#endif
}

__device__ __forceinline__ float sigmoidf_(float x) {
    return 1.f / (1.f + __expf(-x));
}
__device__ __forceinline__ float tanhf_(float x) {
    return 1.f - 2.f / (__expf(2.f * x) + 1.f);
}

// ---------------------------------------------------------------------------
// Kernel 1: eproj[v][g] = emb[v] . W_ih[g] + b_ih[g] + b_hh[g]   (fp32, exact)
// ---------------------------------------------------------------------------
__global__ __launch_bounds__(1024) void eproj_kernel(
    const float* __restrict__ emb, const float* __restrict__ W_ih,
    const float* __restrict__ b_ih, const float* __restrict__ b_hh,
    float* __restrict__ eproj)
{
    const int v = blockIdx.x;
    const int g = threadIdx.x;
    __shared__ __align__(16) float x_sh[EMB];
    if (g < EMB / 4) {
        ((float4*)x_sh)[g] = ((const float4*)(emb + (size_t)v * EMB))[g];
    }
    __syncthreads();
    const float4* wrow = (const float4*)(W_ih + (size_t)g * EMB);
    float a0 = 0.f, a1 = 0.f, a2 = 0.f, a3 = 0.f;
#pragma unroll
    for (int e4 = 0; e4 < EMB / 4; e4++) {
        float4 wv = wrow[e4];
        float4 xv = ((const float4*)x_sh)[e4];
        a0 += wv.x * xv.x;
        a1 += wv.y * xv.y;
        a2 += wv.z * xv.z;
        a3 += wv.w * xv.w;
    }
    eproj[(size_t)v * G4 + g] = (a0 + a1) + (a2 + a3) + b_ih[g] + b_hh[g];
}

// ---------------------------------------------------------------------------
// Kernel 2: pack W_hh fp32 -> fp16 half2 into two [chunk][row][4] u32 arrays:
// wvq (cols 0..91, 23 chunks) register part, wlq (cols 92..127, 9 chunks)
// LDS part. [chunk][row][4] makes both global loads and LDS b128 reads
// lane-consecutive (canonical conflict-free float4 pattern).
// ---------------------------------------------------------------------------
__global__ __launch_bounds__(128) void pack_whh(
    const float* __restrict__ Whh, u32* __restrict__ wvq, u32* __restrict__ wlq)
{
    const int r = blockIdx.x;        // row 0..1023
    const int m = threadIdx.x;       // half2 col 0..127
    H2U u;
    u.h.x = (f16)Whh[(size_t)r * HID + 2 * m];
    u.h.y = (f16)Whh[(size_t)r * HID + 2 * m + 1];
    if (m < KV) {
        wvq[(size_t)(m >> 2) * (G4 * 4) + r * 4 + (m & 3)] = u.u;
    } else {
        const int mm = m - KV;
        wlq[(size_t)(mm >> 2) * (G4 * 4) + r * 4 + (mm & 3)] = u.u;
    }
}

// ---------------------------------------------------------------------------
// Kernel 3: single-CU LSTM, one 1024-thread block (16 waves = 4 waves/SIMD)
// per batch element. CORRECTED occupancy model: per-SIMD unified reg pool is
// 512 (m69: waves halve at 64/128/256), so 4 waves/SIMD caps each wave at
// 128 unified regs. Thread tau owns exactly ONE gate row (row = tau):
// KV=92 half2 cols persistent in regs + ~25 temps fits the 128 cap; the
// 36-col tail (144 KB) stays in LDS. Per-CU totals are unchanged vs the
// 1660us version (VALU 1024 cy/step/SIMD, LDS tail ~1150 cy/step/CU on a
// DIFFERENT pipe) -- the win is 4-deep wave rotation per SIMD, which covers
// the 4-cy fdot2 dependence chain (vs 2-cy issue) and the ds_read latency
// that left the 2-wave/SIMD version at ~31% VALU duty. Accumulation order
// per row is bit-identical to the 1660us kernel.
// ---------------------------------------------------------------------------
__global__ __launch_bounds__(1024, 4) void lstm_single_cu(
    const int* __restrict__ ids, const int* __restrict__ lens,
    const float* __restrict__ eproj,
    const u32* __restrict__ wvq, const u32* __restrict__ wlq,
    float* __restrict__ out)
{
    const int b   = blockIdx.x;
    const int tau = threadIdx.x;                 // 0..1023 == its gate row

    __shared__ u32   wl_sh[KL / 4 * G4 * 4];     // 9 chunks x 1024 rows x 16B
    __shared__ u32   h2_sh[2][HID / 2];          // h as half2, parity x2
    __shared__ float gs_f[HID], gs_g[HID], gs_o[HID];  // gate-sum bounce
    __shared__ int   id_sh[SEQT];                // this block's id row (4 KB)

    const int* idr = ids + (size_t)b * SEQT;
    id_sh[tau] = idr[tau];                       // 1024 x 4B
    if (tau < HID / 2) h2_sh[0][tau] = 0u;       // h(0) = 0

    // stage LDS weight tail (b128 both sides, coalesced)
    {
        const uint4* src = (const uint4*)wlq;
        uint4*       dst = (uint4*)wl_sh;
#pragma unroll
        for (int t = 0; t < (KL / 4) * G4 / 1024; t++)   // 9 iters
            dst[t * 1024 + tau] = src[t * 1024 + tau];
    }

    // persistent VGPR weights: 1 row x 92 half2 = 92 regs
    u32 wA[KV];
#pragma unroll
    for (int q = 0; q < KV / 4; q++) {
        uint4 ta = ((const uint4*)wvq)[q * G4 + tau];
        wA[4 * q + 0] = ta.x; wA[4 * q + 1] = ta.y;
        wA[4 * q + 2] = ta.z; wA[4 * q + 3] = ta.w;
    }

    const int len = lens[b];                     // >= 1
    const int g2  = tau >> 8;                    // gate index: 0=i,1=f,2=g,3=o
    const int u   = tau & (HID - 1);             // unit within gate
    float c = 0.f, hf = 0.f;

    float xA = eproj[(size_t)idr[0] * G4 + tau];

    __syncthreads();

    for (int t = 0; t < len; t++) {
        // prefetch next step's input projection (hidden under dot loops)
        const int nt = (t + 1 < len) ? t + 1 : len - 1;
        const int nid = id_sh[nt];
        const float nA = eproj[(size_t)nid * G4 + tau];

        const int p = t & 1;
        const uint4* hb4 = (const uint4*)h2_sh[p];   // 32 b128 broadcasts
        float aA = xA;

        // register cols 0..91 (23 chunks)
#pragma unroll
        for (int q = 0; q < KV / 4; q++) {
            uint4 h4 = hb4[q];
            aA = fdot2_(wA[4 * q + 0], h4.x, aA);
            aA = fdot2_(wA[4 * q + 1], h4.y, aA);
            aA = fdot2_(wA[4 * q + 2], h4.z, aA);
            aA = fdot2_(wA[4 * q + 3], h4.w, aA);
        }
        // LDS tail cols 92..127 (lane-consecutive b128, conflict-free)
#pragma unroll
        for (int q = 0; q < KL / 4; q++) {
            uint4 h4 = hb4[KV / 4 + q];
            uint4 tA = ((const uint4*)wl_sh)[q * G4 + tau];
            aA = fdot2_(tA.x, h4.x, aA);
            aA = fdot2_(tA.y, h4.y, aA);
            aA = fdot2_(tA.z, h4.z, aA);
            aA = fdot2_(tA.w, h4.w, aA);
        }

        // bounce f,g,o sums to the unit owner (branch is wave-uniform:
        // g2 is constant across each 64-lane wave)
        if (g2 == 1)      gs_f[u] = aA;
        else if (g2 == 2) gs_g[u] = aA;
        else if (g2 == 3) gs_o[u] = aA;
        __syncthreads();             // barrier A: sums visible

        if (g2 == 0) {               // unit owner: i local + f,g,o from LDS
            float ig = sigmoidf_(aA);
            float fg = sigmoidf_(gs_f[u]);
            float gg = tanhf_(gs_g[u]);
            float og = sigmoidf_(gs_o[u]);
            c = fg * c + ig * gg;
            hf = og * tanhf_(c);
            H2U hv; hv.h.x = (f16)hf; hv.h.y = (f16)0.f;
            ((unsigned short*)h2_sh[p ^ 1])[u] = hv.s[0];
        }
        xA = nA;
        __syncthreads();             // barrier B: h(t+1) published
    }

    if (tau < HID) out[(size_t)b * HID + tau] = hf;
}

// ---------------------------------------------------------------------------
// Fallback (ws too small): correct-but-slow single-block fp32 version.
// ---------------------------------------------------------------------------
__global__ __launch_bounds__(1024, 1) void lstm_fallback(
    const int* __restrict__ ids, const int* __restrict__ lens,
    const float* __restrict__ emb, const float* __restrict__ W_ih,
    const float* __restrict__ b_ih, const float* __restrict__ b_hh,
    const float* __restrict__ W_hh, float* __restrict__ out)
{
    const int b = blockIdx.x;
    const int t = threadIdx.x;

    __shared__ __align__(16) float h_sh[HID];
    __shared__ __align__(16) float c_sh[HID];
    __shared__ __align__(16) float gates[G4];
    __shared__ __align__(16) float x_sh[EMB];

    float wih[EMB];
    {
        const float4* wr = (const float4*)(W_ih + (size_t)t * EMB);
#pragma unroll
        for (int e4 = 0; e4 < EMB / 4; e4++) {
            float4 wv = wr[e4];
            wih[4 * e4 + 0] = wv.x;
            wih[4 * e4 + 1] = wv.y;
            wih[4 * e4 + 2] = wv.z;
            wih[4 * e4 + 3] = wv.w;
        }
    }
    float bias = b_ih[t] + b_hh[t];

    const int len = lens[b];
    const int* ids_row = ids + (size_t)b * SEQT;
    if (t < HID) { h_sh[t] = 0.f; c_sh[t] = 0.f; }
    __syncthreads();

    for (int step = 0; step < len; step++) {
        int id = ids_row[step];
        if (t < EMB / 4) {
            ((float4*)x_sh)[t] = ((const float4*)(emb + (size_t)id * EMB))[t];
        }
        __syncthreads();
        float a0 = bias, a1 = 0.f, a2 = 0.f, a3 = 0.f;
#pragma unroll
        for (int e4 = 0; e4 < EMB / 4; e4++) {
            float4 xv = ((const float4*)x_sh)[e4];
            a0 += wih[4 * e4 + 0] * xv.x;
            a1 += wih[4 * e4 + 1] * xv.y;
            a2 += wih[4 * e4 + 2] * xv.z;
            a3 += wih[4 * e4 + 3] * xv.w;
        }
        float acc = (a0 + a1) + (a2 + a3);

        const float* wrow = W_hh + (size_t)t * HID;
        a0 = acc; a1 = 0.f; a2 = 0.f; a3 = 0.f;
        for (int k4 = 0; k4 < HID / 4; k4++) {
            float4 hv = ((const float4*)h_sh)[k4];
            float4 wv = ((const float4*)wrow)[k4];
            a0 += wv.x * hv.x;
            a1 += wv.y * hv.y;
            a2 += wv.z * hv.z;
            a3 += wv.w * hv.w;
        }
        gates[t] = (a0 + a1) + (a2 + a3);
        __syncthreads();

        if (t < HID) {
            float ig = sigmoidf_(gates[t]);
            float fg = sigmoidf_(gates[HID + t]);
            float gg = tanhf_(gates[2 * HID + t]);
            float og = sigmoidf_(gates[3 * HID + t]);
            float cc = fg * c_sh[t] + ig * gg;
            c_sh[t] = cc;
            h_sh[t] = og * tanhf_(cc);
        }
        __syncthreads();
    }
    if (t < HID) out[(size_t)b * HID + t] = h_sh[t];
}

extern "C" void kernel_launch(void* const* d_in, const int* in_sizes, int n_in,
                              void* d_out, int out_size, void* d_ws, size_t ws_size,
                              hipStream_t stream) {
    const int*   ids  = (const int*)d_in[0];
    const int*   lens = (const int*)d_in[1];
    const float* emb  = (const float*)d_in[2];
    const float* Wih  = (const float*)d_in[3];
    const float* Whh  = (const float*)d_in[4];
    const float* bih  = (const float*)d_in[5];
    const float* bhh  = (const float*)d_in[6];
    float* out = (float*)d_out;

    // ws layout: eproj 4 MB | wvq 368 KB | wlq 144 KB
    const size_t ep_bytes = (size_t)VOCAB * G4 * sizeof(float);
    const size_t wv_off   = ep_bytes;
    const size_t wv_bytes = (size_t)(KV / 4) * G4 * 4 * sizeof(u32);
    const size_t wl_off   = wv_off + wv_bytes;
    const size_t wl_bytes = (size_t)(KL / 4) * G4 * 4 * sizeof(u32);

    if (ws_size >= wl_off + wl_bytes) {
        float* eproj = (float*)d_ws;
        u32*   wvp   = (u32*)((char*)d_ws + wv_off);
        u32*   wlp   = (u32*)((char*)d_ws + wl_off);
        eproj_kernel<<<VOCAB, 1024, 0, stream>>>(emb, Wih, bih, bhh, eproj);
        pack_whh<<<G4, 128, 0, stream>>>(Whh, wvp, wlp);
        lstm_single_cu<<<BATCH, 1024, 0, stream>>>(ids, lens, eproj, wvp, wlp, out);
    } else {
        lstm_fallback<<<BATCH, 1024, 0, stream>>>(
            ids, lens, emb, Wih, bih, bhh, Whh, out);
    }
}

// Round 4
// 2014.244 us; speedup vs baseline: 1.6362x; 1.0531x over previous
//
#include <hip/hip_runtime.h>
#include <math.h>

#define VOCAB 1000
#define EMB   128
#define HID   256
#define G4    1024   // 4*HID
#define BATCH 64
#define SEQT  1024
#define KV    92     // half2 cols in VGPRs  (k in [0,184))
#define KL    36     // half2 cols in LDS    (k in [184,256)), 9 b128 chunks

typedef unsigned int u32;
typedef _Float16 f16;
typedef __attribute__((ext_vector_type(2))) _Float16 h2v;
union H2U { u32 u; h2v h; unsigned short s[2]; };

#if defined(__has_builtin)
# if __has_builtin(__builtin_amdgcn_fdot2)
#  define HAVE_FDOT2 1
# endif
#endif
__device__ __forceinline__ float fdot2_(u32 a, u32 b, float c) {
    H2U ua, ub; ua.u = a; ub.u = b;
#ifdef HAVE_FDOT2
    return __builtin_amdgcn_fdot2(ua.h, ub.h, c, false);   // v_dot2_f32_f16
#else
    return c + (float)ua.h.x * (float)ub.h.x + (float)ua.h.y * (float)ub.h.y;
#endif
}

// wave-uniform h fetch: constant lane index after unroll -> v_readlane_b32
__device__ __forceinline__ u32 rl_(u32 hv0, u32 hv1, int idx) {
    return (u32)__builtin_amdgcn_readlane((int)(idx < 64 ? hv0 : hv1), idx & 63);
}

__device__ __forceinline__ float sigmoidf_(float x) {
    return 1.f / (1.f + __expf(-x));
}
__device__ __forceinline__ float tanhf_(float x) {
    return 1.f - 2.f / (__expf(2.f * x) + 1.f);
}

// ---------------------------------------------------------------------------
// Kernel 1: eproj[v][g] = emb[v] . W_ih[g] + b_ih[g] + b_hh[g]   (fp32, exact)
// ---------------------------------------------------------------------------
__global__ __launch_bounds__(1024) void eproj_kernel(
    const float* __restrict__ emb, const float* __restrict__ W_ih,
    const float* __restrict__ b_ih, const float* __restrict__ b_hh,
    float* __restrict__ eproj)
{
    const int v = blockIdx.x;
    const int g = threadIdx.x;
    __shared__ __align__(16) float x_sh[EMB];
    if (g < EMB / 4) {
        ((float4*)x_sh)[g] = ((const float4*)(emb + (size_t)v * EMB))[g];
    }
    __syncthreads();
    const float4* wrow = (const float4*)(W_ih + (size_t)g * EMB);
    float a0 = 0.f, a1 = 0.f, a2 = 0.f, a3 = 0.f;
#pragma unroll
    for (int e4 = 0; e4 < EMB / 4; e4++) {
        float4 wv = wrow[e4];
        float4 xv = ((const float4*)x_sh)[e4];
        a0 += wv.x * xv.x;
        a1 += wv.y * xv.y;
        a2 += wv.z * xv.z;
        a3 += wv.w * xv.w;
    }
    eproj[(size_t)v * G4 + g] = (a0 + a1) + (a2 + a3) + b_ih[g] + b_hh[g];
}

// ---------------------------------------------------------------------------
// Kernel 2: pack W_hh fp32 -> fp16 half2 into two [chunk][row][4] u32 arrays:
// wvq (cols 0..91, 23 chunks) register part, wlq (cols 92..127, 9 chunks)
// LDS part. [chunk][row][4] makes both global loads and LDS b128 reads
// lane-consecutive (canonical conflict-free float4 pattern).
// ---------------------------------------------------------------------------
__global__ __launch_bounds__(128) void pack_whh(
    const float* __restrict__ Whh, u32* __restrict__ wvq, u32* __restrict__ wlq)
{
    const int r = blockIdx.x;        // row 0..1023
    const int m = threadIdx.x;       // half2 col 0..127
    H2U u;
    u.h.x = (f16)Whh[(size_t)r * HID + 2 * m];
    u.h.y = (f16)Whh[(size_t)r * HID + 2 * m + 1];
    if (m < KV) {
        wvq[(size_t)(m >> 2) * (G4 * 4) + r * 4 + (m & 3)] = u.u;
    } else {
        const int mm = m - KV;
        wlq[(size_t)(mm >> 2) * (G4 * 4) + r * 4 + (mm & 3)] = u.u;
    }
}

// ---------------------------------------------------------------------------
// Kernel 3: single-CU LSTM, 512 thr (8 waves, 2/SIMD, 256-unified-reg cap)
// per batch element -- the proven 1660us structure, with the h-broadcast
// moved OFF the LDS pipe. Evidence (R0 vs R3 counters): step time tracks
// total LDS instruction count (R3 doubled broadcasts -> +850cy/step), and
// R0 spends ~2000-3200 cy/step on the LDS pipe (tail 1150 bank-cy + 256
// h-broadcast b128s) vs a 1024-cy VALU floor. Changes:
//  (a) h is read once/step as 2 lane-spread ds_read_b32 (2-way alias=free),
//      then distributed via v_readlane (SGPR, wave-uniform) -- 256 LDS
//      broadcast instrs/step and their per-chunk ds latency chains vanish;
//      freed VGPR temps let the compiler pipeline the 9 tail reads deeper.
//  (b) gates pre-activated before the bounce: serial post-barrier path is
//      just c=fg*c+ig*gg; h=og*tanh(c). Same fp32 values/ops -> identical
//      numerics. Zero cross-CU traffic.
// ---------------------------------------------------------------------------
__global__ __launch_bounds__(512, 2) void lstm_single_cu(
    const int* __restrict__ ids, const int* __restrict__ lens,
    const float* __restrict__ eproj,
    const u32* __restrict__ wvq, const u32* __restrict__ wlq,
    float* __restrict__ out)
{
    const int b   = blockIdx.x;
    const int tau = threadIdx.x;                 // 0..511
    const int rA  = tau;                         // gate i (tau<256) / f
    const int rB  = 512 + tau;                   // gate g (tau<256) / o
    const int ln  = tau & 63;                    // lane

    __shared__ u32   wl_sh[KL / 4 * G4 * 4];     // 9 chunks x 1024 rows x 16B
    __shared__ u32   h2_sh[2][HID / 2];          // h as half2, parity x2
    __shared__ float gs_f[HID], gs_o[HID];       // ACTIVATED f,o bounce
    __shared__ int   id_sh[SEQT];                // this block's id row (4 KB)

    const int* idr = ids + (size_t)b * SEQT;
    ((int2*)id_sh)[tau] = ((const int2*)idr)[tau];   // 512 x 8B = 4 KB
    if (tau < HID / 2) h2_sh[0][tau] = 0u;           // h(0) = 0

    // stage LDS weight tail (b128 both sides, coalesced)
    {
        const uint4* src = (const uint4*)wlq;
        uint4*       dst = (uint4*)wl_sh;
#pragma unroll
        for (int t = 0; t < (KL / 4) * G4 / 512; t++)   // 18 iters
            dst[t * 512 + tau] = src[t * 512 + tau];
    }

    // persistent VGPR weights: 2 rows x 92 half2 = 184 regs
    u32 wA[KV], wB[KV];
#pragma unroll
    for (int q = 0; q < KV / 4; q++) {
        uint4 ta = ((const uint4*)wvq)[q * G4 + rA];
        uint4 tb = ((const uint4*)wvq)[q * G4 + rB];
        wA[4 * q + 0] = ta.x; wA[4 * q + 1] = ta.y;
        wA[4 * q + 2] = ta.z; wA[4 * q + 3] = ta.w;
        wB[4 * q + 0] = tb.x; wB[4 * q + 1] = tb.y;
        wB[4 * q + 2] = tb.z; wB[4 * q + 3] = tb.w;
    }

    const int len = lens[b];                     // >= 1
    float c = 0.f, hf = 0.f;

    const float* e0 = eproj + (size_t)idr[0] * G4;
    float xA = e0[rA], xB = e0[rB];

    __syncthreads();

    for (int t = 0; t < len; t++) {
        // prefetch next step's input projections (hidden under dot loops)
        const int nt = (t + 1 < len) ? t + 1 : len - 1;
        const int nid = id_sh[nt];
        const float* en = eproj + (size_t)nid * G4;
        const float nA = en[rA], nB = en[rB];

        const int p = t & 1;
        // h for this step: one lane-spread read pair, then SGPR readlanes
        const u32 hv0 = h2_sh[p][ln];            // h2 words 0..63
        const u32 hv1 = h2_sh[p][64 + ln];       // h2 words 64..127
        float aA = xA, aB = xB;

        // register cols 0..91 (23 chunks); h via v_readlane (wave-uniform)
#pragma unroll
        for (int q = 0; q < KV / 4; q++) {
            u32 h0 = rl_(hv0, hv1, 4 * q + 0);
            u32 h1 = rl_(hv0, hv1, 4 * q + 1);
            u32 h2 = rl_(hv0, hv1, 4 * q + 2);
            u32 h3 = rl_(hv0, hv1, 4 * q + 3);
            aA = fdot2_(wA[4 * q + 0], h0, aA);
            aB = fdot2_(wB[4 * q + 0], h0, aB);
            aA = fdot2_(wA[4 * q + 1], h1, aA);
            aB = fdot2_(wB[4 * q + 1], h1, aB);
            aA = fdot2_(wA[4 * q + 2], h2, aA);
            aB = fdot2_(wB[4 * q + 2], h2, aB);
            aA = fdot2_(wA[4 * q + 3], h3, aA);
            aB = fdot2_(wB[4 * q + 3], h3, aB);
        }
        // LDS tail cols 92..127 (lane-consecutive b128, conflict-free)
#pragma unroll
        for (int q = 0; q < KL / 4; q++) {
            u32 h0 = rl_(hv0, hv1, KV + 4 * q + 0);
            u32 h1 = rl_(hv0, hv1, KV + 4 * q + 1);
            u32 h2 = rl_(hv0, hv1, KV + 4 * q + 2);
            u32 h3 = rl_(hv0, hv1, KV + 4 * q + 3);
            uint4 tA = ((const uint4*)wl_sh)[q * G4 + rA];
            uint4 tB = ((const uint4*)wl_sh)[q * G4 + rB];
            aA = fdot2_(tA.x, h0, aA);
            aB = fdot2_(tB.x, h0, aB);
            aA = fdot2_(tA.y, h1, aA);
            aB = fdot2_(tB.y, h1, aB);
            aA = fdot2_(tA.z, h2, aA);
            aB = fdot2_(tB.z, h2, aB);
            aA = fdot2_(tA.w, h3, aA);
            aB = fdot2_(tB.w, h3, aB);
        }

        // pre-activate in parallel, then bounce ACTIVATED f,o
        float ig = 0.f, gg = 0.f;
        if (tau >= HID) {            // rows f,o: sigmoid here (parallel)
            gs_f[tau - HID] = sigmoidf_(aA);
            gs_o[tau - HID] = sigmoidf_(aB);
        } else {                     // rows i,g: activate own gates now
            ig = sigmoidf_(aA);
            gg = tanhf_(aB);
        }
        __syncthreads();             // barrier A: activated sums visible

        if (tau < HID) {             // unit owner: short serial path
            c  = gs_f[tau] * c + ig * gg;
            hf = gs_o[tau] * tanhf_(c);
            H2U hv; hv.h.x = (f16)hf; hv.h.y = (f16)0.f;
            ((unsigned short*)h2_sh[p ^ 1])[tau] = hv.s[0];
        }
        xA = nA; xB = nB;
        __syncthreads();             // barrier B: h(t+1) published
    }

    if (tau < HID) out[(size_t)b * HID + tau] = hf;
}

// ---------------------------------------------------------------------------
// Fallback (ws too small): correct-but-slow single-block fp32 version.
// ---------------------------------------------------------------------------
__global__ __launch_bounds__(1024, 1) void lstm_fallback(
    const int* __restrict__ ids, const int* __restrict__ lens,
    const float* __restrict__ emb, const float* __restrict__ W_ih,
    const float* __restrict__ b_ih, const float* __restrict__ b_hh,
    const float* __restrict__ W_hh, float* __restrict__ out)
{
    const int b = blockIdx.x;
    const int t = threadIdx.x;

    __shared__ __align__(16) float h_sh[HID];
    __shared__ __align__(16) float c_sh[HID];
    __shared__ __align__(16) float gates[G4];
    __shared__ __align__(16) float x_sh[EMB];

    float wih[EMB];
    {
        const float4* wr = (const float4*)(W_ih + (size_t)t * EMB);
#pragma unroll
        for (int e4 = 0; e4 < EMB / 4; e4++) {
            float4 wv = wr[e4];
            wih[4 * e4 + 0] = wv.x;
            wih[4 * e4 + 1] = wv.y;
            wih[4 * e4 + 2] = wv.z;
            wih[4 * e4 + 3] = wv.w;
        }
    }
    float bias = b_ih[t] + b_hh[t];

    const int len = lens[b];
    const int* ids_row = ids + (size_t)b * SEQT;
    if (t < HID) { h_sh[t] = 0.f; c_sh[t] = 0.f; }
    __syncthreads();

    for (int step = 0; step < len; step++) {
        int id = ids_row[step];
        if (t < EMB / 4) {
            ((float4*)x_sh)[t] = ((const float4*)(emb + (size_t)id * EMB))[t];
        }
        __syncthreads();
        float a0 = bias, a1 = 0.f, a2 = 0.f, a3 = 0.f;
#pragma unroll
        for (int e4 = 0; e4 < EMB / 4; e4++) {
            float4 xv = ((const float4*)x_sh)[e4];
            a0 += wih[4 * e4 + 0] * xv.x;
            a1 += wih[4 * e4 + 1] * xv.y;
            a2 += wih[4 * e4 + 2] * xv.z;
            a3 += wih[4 * e4 + 3] * xv.w;
        }
        float acc = (a0 + a1) + (a2 + a3);

        const float* wrow = W_hh + (size_t)t * HID;
        a0 = acc; a1 = 0.f; a2 = 0.f; a3 = 0.f;
        for (int k4 = 0; k4 < HID / 4; k4++) {
            float4 hv = ((const float4*)h_sh)[k4];
            float4 wv = ((const float4*)wrow)[k4];
            a0 += wv.x * hv.x;
            a1 += wv.y * hv.y;
            a2 += wv.z * hv.z;
            a3 += wv.w * hv.w;
        }
        gates[t] = (a0 + a1) + (a2 + a3);
        __syncthreads();

        if (t < HID) {
            float ig = sigmoidf_(gates[t]);
            float fg = sigmoidf_(gates[HID + t]);
            float gg = tanhf_(gates[2 * HID + t]);
            float og = sigmoidf_(gates[3 * HID + t]);
            float cc = fg * c_sh[t] + ig * gg;
            c_sh[t] = cc;
            h_sh[t] = og * tanhf_(cc);
        }
        __syncthreads();
    }
    if (t < HID) out[(size_t)b * HID + t] = h_sh[t];
}

extern "C" void kernel_launch(void* const* d_in, const int* in_sizes, int n_in,
                              void* d_out, int out_size, void* d_ws, size_t ws_size,
                              hipStream_t stream) {
    const int*   ids  = (const int*)d_in[0];
    const int*   lens = (const int*)d_in[1];
    const float* emb  = (const float*)d_in[2];
    const float* Wih  = (const float*)d_in[3];
    const float* Whh  = (const float*)d_in[4];
    const float* bih  = (const float*)d_in[5];
    const float* bhh  = (const float*)d_in[6];
    float* out = (float*)d_out;

    // ws layout: eproj 4 MB | wvq 368 KB | wlq 144 KB
    const size_t ep_bytes = (size_t)VOCAB * G4 * sizeof(float);
    const size_t wv_off   = ep_bytes;
    const size_t wv_bytes = (size_t)(KV / 4) * G4 * 4 * sizeof(u32);
    const size_t wl_off   = wv_off + wv_bytes;
    const size_t wl_bytes = (size_t)(KL / 4) * G4 * 4 * sizeof(u32);

    if (ws_size >= wl_off + wl_bytes) {
        float* eproj = (float*)d_ws;
        u32*   wvp   = (u32*)((char*)d_ws + wv_off);
        u32*   wlp   = (u32*)((char*)d_ws + wl_off);
        eproj_kernel<<<VOCAB, 1024, 0, stream>>>(emb, Wih, bih, bhh, eproj);
        pack_whh<<<G4, 128, 0, stream>>>(Whh, wvp, wlp);
        lstm_single_cu<<<BATCH, 512, 0, stream>>>(ids, lens, eproj, wvp, wlp, out);
    } else {
        lstm_fallback<<<BATCH, 1024, 0, stream>>>(
            ids, lens, emb, Wih, bih, bhh, Whh, out);
    }
}